// Round 6
// baseline (26.786 us; speedup 1.0000x reference)
//
#include <hip/hip_runtime.h>
#include <hip/hip_fp16.h>
#include <math.h>

#define D 64
#define NS 64      // S: tokens per shard
#define H 8
#define NSHARD 128 // B * n_shards
#define KPB 4      // k columns per block (1 per wave)
#define NBLK (NSHARD * (D / KPB))   // 2048 blocks = 8/CU exactly
#define TBL 512    // LUT entries over [-8, 8), nearest-neighbor (centers baked)
constexpr float LR = 0.01f;
constexpr float WD = 0.01f;
constexpr float GSCALE = (float)TBL / 16.0f;   // 32 entries per unit g
constexpr float GOFF   = 8.0f * GSCALE;        // 256
constexpr float TMAXN  = 511.0f;               // clamp for nearest index

typedef __attribute__((ext_vector_type(8))) short bf16x8;  // 8 bf16 (4 VGPR)
typedef __attribute__((ext_vector_type(4))) float f32x4;

__device__ __forceinline__ short f2bf(float f) {           // f32 -> bf16 RNE
    unsigned u = __float_as_uint(f);
    return (short)((u + 0x7FFF + ((u >> 16) & 1)) >> 16);
}

template<int CTRL, int RM>
__device__ __forceinline__ float dpp_add(float v) {
    int t = __builtin_amdgcn_update_dpp(0, __float_as_int(v), CTRL, RM, 0xf, true);
    return v + __int_as_float(t);
}

// LDS layout (20480 B -> 8 blocks/CU EXACTLY: 8*20480 = 163840):
//   prep:  [0,18432)  WT[2][64][72] bf16  (W0^T + Wq^T staging)
//   main:  [0,17408)  XQT[64 j][68 s] u32 (half2(x,q), row=j col=s) -- overlays WT
//          [17408,18432) Esm[64][4] f32   (this block's 4 k-cols of E) -- overlays WT tail
//   both:  [18432,20480) Tl[512] f32 (nearest LUT, cell centers)
// Overlay discipline: barrier after all WT reads; Esm/XQT written from registers after it.
#define SM_BYTES 20480
#define OFF_ESM  17408
#define OFF_TL   18432

__global__ __launch_bounds__(256, 8) void tnt_fused(const float* __restrict__ X,
                                                    const float* __restrict__ mem0,
                                                    const float* __restrict__ opt,
                                                    const float* __restrict__ Wq,
                                                    float* __restrict__ out) {
    __shared__ __align__(16) char smem[SM_BYTES];
    short*    WT  = (short*)(smem);               // [2][64][72] (prep only)
    unsigned* XQT = (unsigned*)(smem);            // [64][68]   (main loop)
    float (*Esm)[KPB] = (float(*)[KPB])(smem + OFF_ESM);
    float*    Tl  = (float*)(smem + OFF_TL);

    // XCD swizzle: the 16 blocks of a shard land on one XCD's L2 (2048 % 8 == 0)
    const int bid  = ((int)blockIdx.x & 7) * (NBLK / 8) + ((int)blockIdx.x >> 3);
    const int n    = bid >> 4;
    const int kq   = bid & 15;
    const int tid  = threadIdx.x;
    const int wv   = tid >> 6;
    const int lane = tid & 63;
    const int l15  = lane & 15, lhi = lane >> 4;
    const int k0   = (kq << 2) + wv;              // this wave's k column

    const float* Xs = X + n * NS * D;

    // ---- phase 1: stage W0^T and Wq^T bf16 in one pass ----
    {
        const int m     = tid >> 7;            // matrix 0/1
        const int kcol  = tid & 63;            // output column of W
        const int gbase = ((tid >> 6) & 1) * 4;
        const float* Wm = m ? Wq : mem0;
#pragma unroll
        for (int gg = 0; gg < 4; ++gg) {
            const int g = gbase + gg;
            bf16x8 pk;
#pragma unroll
            for (int i = 0; i < 8; ++i)
                pk[i] = f2bf(Wm[(g * 8 + i) * D + kcol]);   // coalesced per i
            *(bf16x8*)(WT + (m * 64 + kcol) * 72 + g * 8) = pk;
        }
    }
    // A-frags (rows wv*16 + l15), shared by both GEMMs
    bf16x8 afrag[2];
    {
        const float* xrow = Xs + (wv * 16 + l15) * D + lhi * 8;
#pragma unroll
        for (int ks = 0; ks < 2; ++ks) {
            const float4 u0 = *(const float4*)(xrow + ks * 32);
            const float4 u1 = *(const float4*)(xrow + ks * 32 + 4);
            bf16x8 a;
            a[0]=f2bf(u0.x); a[1]=f2bf(u0.y); a[2]=f2bf(u0.z); a[3]=f2bf(u0.w);
            a[4]=f2bf(u1.x); a[5]=f2bf(u1.y); a[6]=f2bf(u1.z); a[7]=f2bf(u1.w);
            afrag[ks] = a;
        }
    }
    const float m0v  = mem0[lane * D + k0];
    const float wdm0 = WD * m0v;
    __syncthreads();

    // ---- phase 2: E GEMM -> regs; Q GEMM -> regs; LUT ----
    float eEr[4];
    const bool ewr  = (l15 >> 2) == (kq & 3);
    const int  erow = wv * 16 + lhi * 4;
    {
        f32x4 accE[4];
#pragma unroll
        for (int nt = 0; nt < 4; ++nt) accE[nt] = 0;
#pragma unroll
        for (int nt = 0; nt < 4; ++nt) {
            const int col = nt * 16 + l15;
#pragma unroll
            for (int ks = 0; ks < 2; ++ks) {
                const bf16x8 b0 = *(const bf16x8*)(WT + col * 72 + ks * 32 + lhi * 8);
                accE[nt] = __builtin_amdgcn_mfma_f32_16x16x32_bf16(afrag[ks], b0, accE[nt], 0,0,0);
            }
        }
        const float c = (2.0f / (float)D) * GSCALE;
        const int nt_e = kq >> 2;                // wave-uniform select (no scratch)
        const f32x4 aE = (nt_e == 0) ? accE[0] : (nt_e == 1) ? accE[1]
                       : (nt_e == 2) ? accE[2] : accE[3];
        const int ecol = (kq << 2) + (l15 & 3);
        if (ewr) {
#pragma unroll
            for (int r = 0; r < 4; ++r)
                eEr[r] = c * (aE[r] - Xs[(erow + r) * D + ecol]);
        }
    }
    f32x4 accQ[4];                               // held across the barrier
    {
#pragma unroll
        for (int nt = 0; nt < 4; ++nt) accQ[nt] = 0;
#pragma unroll
        for (int nt = 0; nt < 4; ++nt) {
            const int col = nt * 16 + l15;
#pragma unroll
            for (int ks = 0; ks < 2; ++ks) {
                const bf16x8 b1 = *(const bf16x8*)(WT + (64 + col) * 72 + ks * 32 + lhi * 8);
                accQ[nt] = __builtin_amdgcn_mfma_f32_16x16x32_bf16(afrag[ks], b1, accQ[nt], 0,0,0);
            }
        }
    }
    {   // LR-scaled nearest LUT: entry j = f at cell center g=(j+0.5-256)/32
        float w1d[H], b1d[H], w2[H];
#pragma unroll
        for (int h = 0; h < H; ++h) {
            w1d[h] = 2.0f * opt[h]; b1d[h] = 2.0f * opt[H + h]; w2[h] = opt[2 * H + h];
        }
        const float b2 = opt[3 * H];
#pragma unroll
        for (int jj = tid; jj < TBL; jj += 256) {      // 2 iterations
            const float g = ((float)jj + 0.5f - GOFF) / GSCALE;
            float acc = b2;
#pragma unroll
            for (int h = 0; h < H; ++h) {
                const float u = __expf(fmaf(w1d[h], g, b1d[h]));   // e^{2y}
                acc = fmaf(w2[h], (u - 1.0f) * __builtin_amdgcn_rcpf(u + 1.0f), acc);
            }
            Tl[jj] = LR * acc;
        }
    }
    __syncthreads();   // ALL WT reads done -> safe to overlay XQT/Esm

    // ---- phase 3: write Esm (from regs) + XQT (x reload + accQ) ----
    if (ewr) {
#pragma unroll
        for (int r = 0; r < 4; ++r)
            Esm[erow + r][l15 & 3] = eEr[r];
    }
#pragma unroll
    for (int nt = 0; nt < 4; ++nt) {
#pragma unroll
        for (int r = 0; r < 4; ++r) {
            const int row = erow + r;                   // s
            const int col = nt * 16 + l15;              // j
            const __half2 h = __halves2half2(__float2half_rn(Xs[row * D + col]),
                                             __float2half_rn(accQ[nt][r]));
            XQT[col * 68 + row] = *(const unsigned*)&h;
        }
    }
    __syncthreads();   // XQT + Esm ready

    const float e0 = Esm[lane][wv];    // E[n, s=lane, k0] * GSCALE

    // ---- main loop: 8 fully-unrolled batches; in-wave 64-lane reduce; scatter ----
    const unsigned* xrow = XQT + lane * 68;    // this lane's j-column, along s
    float cum = m0v;
    const int  bp32 = ((lane ^ 32) << 2);      // ds_bpermute byte index for xor32
    const bool s1 = (lane & 1) != 0;
    const bool s2 = (lane & 2) != 0;
    const bool s4 = (lane & 4) != 0;
    float* orow = out + (n * NS) * D + k0;

#pragma unroll
    for (int b = 0; b < 8; ++b) {
        const uint4 xa = *(const uint4*)(xrow + b * 8);
        const uint4 xb = *(const uint4*)(xrow + b * 8 + 4);
        const unsigned xw[8] = {xa.x, xa.y, xa.z, xa.w, xb.x, xb.y, xb.z, xb.w};
        float q8[8], v8[8];
#pragma unroll
        for (int u = 0; u < 8; ++u) {          // independent across u
            const int s = (b << 3) + u;
            const float ek = __int_as_float(
                __builtin_amdgcn_readlane(__float_as_int(e0), s));
            const __half2 hv = *(const __half2*)&xw[u];
            const float xv = __low2float(hv);
            q8[u] = __high2float(hv);
            const float t = __builtin_amdgcn_fmed3f(fmaf(xv, ek, GOFF), 0.0f, TMAXN);
            v8[u] = Tl[(int)t] + wdm0;         // single b32 gather per u
        }
        float p8[8];
#pragma unroll
        for (int u = 0; u < 8; ++u) {          // serial cum chain + row-16 DPP reduce
            cum -= v8[u];
            float p = q8[u] * cum;
            p = dpp_add<0xB1,  0xf>(p);        // xor 1
            p = dpp_add<0x4E,  0xf>(p);        // xor 2
            p = dpp_add<0x141, 0xf>(p);        // row_half_mirror -> 8-sum
            p = dpp_add<0x140, 0xf>(p);        // row_mirror      -> 16-sum (bcast in row)
            p8[u] = p;
        }
        // per-lane select: lane picks u = lane&7 (7 cndmask, static idx)
        const float t0 = s1 ? p8[1] : p8[0];
        const float t1 = s1 ? p8[3] : p8[2];
        const float t2 = s1 ? p8[5] : p8[4];
        const float t3 = s1 ? p8[7] : p8[6];
        const float a0 = s2 ? t1 : t0;
        const float a1 = s2 ? t3 : t2;
        float val = s4 ? a1 : a0;
        // cross-row sum: xor16 (ds_swizzle) + xor32 (ds_bpermute); w16/w32 preserved
        val += __int_as_float(__builtin_amdgcn_ds_swizzle(__float_as_int(val), 0x401F));
        val += __int_as_float(__builtin_amdgcn_ds_bpermute(bp32, __float_as_int(val)));
        if (lane < 8)                          // lanes 0..7 hold full sums for u=lane
            orow[((b << 3) + lane) * D] = val;
    }
}

extern "C" void kernel_launch(void* const* d_in, const int* in_sizes, int n_in,
                              void* d_out, int out_size, void* d_ws, size_t ws_size,
                              hipStream_t stream) {
    const float* X    = (const float*)d_in[0];   // (4,2048,64)
    const float* mem0 = (const float*)d_in[1];   // (4096,)
    const float* opt  = (const float*)d_in[2];   // (25,)
    const float* Wq   = (const float*)d_in[3];   // (64,64)
    float* out = (float*)d_out;

    tnt_fused<<<dim3(NBLK), dim3(256), 0, stream>>>(X, mem0, opt, Wq, out);
}